// Round 1
// baseline (452.446 us; speedup 1.0000x reference)
//
#include <hip/hip_runtime.h>
#include <math.h>

#define N_NODES 8192
#define F_IN    512
#define F_OUT   512
#define ALPHA   0.2f

// ---------------------------------------------------------------------------
// Stage 1: partial v1/v2 where v1 = W^T @ a[:512], v2 = W^T @ a[512:].
// 32 blocks x 256 threads; block b handles o in [b*16, b*16+16).
// Thread t covers k = t and k = t+256 (coalesced across t).
// ---------------------------------------------------------------------------
__global__ void k_wpart(const float* __restrict__ W, const float* __restrict__ a,
                        float* __restrict__ p1, float* __restrict__ p2) {
    const int b = blockIdx.x;
    const int t = threadIdx.x;
    const int k1 = t, k2 = t + 256;
    float a1k1 = 0.f, a1k2 = 0.f, a2k1 = 0.f, a2k2 = 0.f;
#pragma unroll
    for (int oo = 0; oo < 16; ++oo) {
        const int o = b * 16 + oo;
        const float a1 = a[o];
        const float a2 = a[F_OUT + o];
        const float w1 = W[(size_t)o * F_IN + k1];
        const float w2 = W[(size_t)o * F_IN + k2];
        a1k1 += w1 * a1;  a1k2 += w2 * a1;
        a2k1 += w1 * a2;  a2k2 += w2 * a2;
    }
    p1[b * 512 + k1] = a1k1;  p1[b * 512 + k2] = a1k2;
    p2[b * 512 + k1] = a2k1;  p2[b * 512 + k2] = a2k2;
}

// Reduce the 32 partials -> v1[512], v2[512]. 2 blocks x 256 threads.
__global__ void k_vreduce(const float* __restrict__ p1, const float* __restrict__ p2,
                          float* __restrict__ v1, float* __restrict__ v2) {
    const int k = blockIdx.x * 256 + threadIdx.x;   // 0..511
    float s1 = 0.f, s2 = 0.f;
#pragma unroll
    for (int b = 0; b < 32; ++b) {
        s1 += p1[b * 512 + k];
        s2 += p2[b * 512 + k];
    }
    v1[k] = s1;
    v2[k] = s2;
}

// ---------------------------------------------------------------------------
// Stage 2: s1[i] = nodes[i,:] . v1 ; s2[i] = nodes[i,:] . v2
// One wave per row; 256-thread blocks = 4 rows/block; 2048 blocks.
// ---------------------------------------------------------------------------
__global__ void k_scores(const float* __restrict__ nodes,
                         const float* __restrict__ v1, const float* __restrict__ v2,
                         float* __restrict__ s1, float* __restrict__ s2) {
    const int wave = threadIdx.x >> 6;
    const int lane = threadIdx.x & 63;
    const int row  = blockIdx.x * 4 + wave;
    const float4* np4 = (const float4*)(nodes + (size_t)row * F_IN);
    const float4* v14 = (const float4*)v1;
    const float4* v24 = (const float4*)v2;
    float acc1 = 0.f, acc2 = 0.f;
#pragma unroll
    for (int i = 0; i < 2; ++i) {
        const int idx = i * 64 + lane;   // float4 index 0..127, lane-consecutive
        const float4 n  = np4[idx];
        const float4 w1 = v14[idx];
        const float4 w2 = v24[idx];
        acc1 += n.x * w1.x + n.y * w1.y + n.z * w1.z + n.w * w1.w;
        acc2 += n.x * w2.x + n.y * w2.y + n.z * w2.z + n.w * w2.w;
    }
#pragma unroll
    for (int off = 32; off; off >>= 1) {
        acc1 += __shfl_xor(acc1, off);
        acc2 += __shfl_xor(acc2, off);
    }
    if (lane == 0) {
        s1[row] = acc1;
        s2[row] = acc2;
    }
}

// ---------------------------------------------------------------------------
// Stage 3: masked leaky-relu softmax per row.
// One block (256 threads) per row; each thread holds 32 columns in registers.
// adj read exactly once; out written exactly once.
// ---------------------------------------------------------------------------
__global__ void __launch_bounds__(256)
k_softmax(const float* __restrict__ adj, const float* __restrict__ s1g,
          const float* __restrict__ s2g, float* __restrict__ out) {
    const int row = blockIdx.x;
    const int tid = threadIdx.x;
    const int wave = tid >> 6;
    const int lane = tid & 63;
    const size_t rowoff = (size_t)row * N_NODES;
    const float s1i = s1g[row];

    const float4* adj4 = (const float4*)(adj + rowoff);
    const float4* s24  = (const float4*)s2g;
    float4* out4 = (float4*)(out + rowoff);

    __shared__ float redmax[4];
    __shared__ float redsum[4];

    float4 t[8];
    float vmax = -INFINITY;

    // Pass 1: compute masked lrelu scores into registers, track max.
#pragma unroll
    for (int it = 0; it < 8; ++it) {
        const int j4 = it * 256 + tid;
        const float4 av = adj4[j4];
        const float4 sv = s24[j4];
        float4 e;
        {
            float x = s1i + sv.x; x = fmaxf(x, ALPHA * x);
            e.x = (av.x >= 0.5f) ? x : -INFINITY;
        }
        {
            float x = s1i + sv.y; x = fmaxf(x, ALPHA * x);
            e.y = (av.y >= 0.5f) ? x : -INFINITY;
        }
        {
            float x = s1i + sv.z; x = fmaxf(x, ALPHA * x);
            e.z = (av.z >= 0.5f) ? x : -INFINITY;
        }
        {
            float x = s1i + sv.w; x = fmaxf(x, ALPHA * x);
            e.w = (av.w >= 0.5f) ? x : -INFINITY;
        }
        vmax = fmaxf(vmax, fmaxf(fmaxf(e.x, e.y), fmaxf(e.z, e.w)));
        t[it] = e;
    }

    // Block-reduce max (4 waves).
#pragma unroll
    for (int off = 32; off; off >>= 1)
        vmax = fmaxf(vmax, __shfl_xor(vmax, off));
    if (lane == 0) redmax[wave] = vmax;
    __syncthreads();
    const float m = fmaxf(fmaxf(redmax[0], redmax[1]), fmaxf(redmax[2], redmax[3]));

    // Pass 2: exponentiate in place, accumulate sum.
    float sum = 0.f;
#pragma unroll
    for (int it = 0; it < 8; ++it) {
        float4 e = t[it];
        e.x = __expf(e.x - m);
        e.y = __expf(e.y - m);
        e.z = __expf(e.z - m);
        e.w = __expf(e.w - m);
        sum += (e.x + e.y) + (e.z + e.w);
        t[it] = e;
    }
#pragma unroll
    for (int off = 32; off; off >>= 1)
        sum += __shfl_xor(sum, off);
    if (lane == 0) redsum[wave] = sum;
    __syncthreads();
    const float total = (redsum[0] + redsum[1]) + (redsum[2] + redsum[3]);
    const float inv = 1.0f / total;

    // Pass 3: normalize and write.
#pragma unroll
    for (int it = 0; it < 8; ++it) {
        const int j4 = it * 256 + tid;
        float4 e = t[it];
        e.x *= inv; e.y *= inv; e.z *= inv; e.w *= inv;
        out4[j4] = e;
    }
}

extern "C" void kernel_launch(void* const* d_in, const int* in_sizes, int n_in,
                              void* d_out, int out_size, void* d_ws, size_t ws_size,
                              hipStream_t stream) {
    const float* nodes = (const float*)d_in[0];   // [8192, 512]
    const float* adj   = (const float*)d_in[1];   // [8192, 8192]
    const float* W     = (const float*)d_in[2];   // [512, 512]
    const float* a     = (const float*)d_in[3];   // [1024]
    float* out = (float*)d_out;                   // [8192, 8192]

    float* ws = (float*)d_ws;
    float* v1 = ws;                     // 512
    float* v2 = ws + 512;               // 512
    float* s1 = ws + 1024;              // 8192
    float* s2 = ws + 1024 + 8192;       // 8192
    float* p1 = ws + 1024 + 16384;      // 32*512
    float* p2 = p1 + 32 * 512;          // 32*512

    k_wpart  <<<32,   256, 0, stream>>>(W, a, p1, p2);
    k_vreduce<<<2,    256, 0, stream>>>(p1, p2, v1, v2);
    k_scores <<<2048, 256, 0, stream>>>(nodes, v1, v2, s1, s2);
    k_softmax<<<8192, 256, 0, stream>>>(adj, s1, s2, out);
}